// Round 1
// baseline (3933.777 us; speedup 1.0000x reference)
//
#include <hip/hip_runtime.h>

#define N_NODES 100000
#define N_EDGES 1600000

// ---------------- degree / norm precompute ----------------

__global__ __launch_bounds__(256) void init_deg(float* deg, int n) {
    int i = blockIdx.x * blockDim.x + threadIdx.x;
    if (i < n) deg[i] = 1.0f;  // self-loop contribution
}

__global__ __launch_bounds__(256) void accum_deg(const int* __restrict__ dst, float* deg, int e) {
    int i = blockIdx.x * blockDim.x + threadIdx.x;
    if (i < e) atomicAdd(&deg[dst[i]], 1.0f);
}

__global__ __launch_bounds__(256) void deg_to_dinv(float* deg, int n) {
    int i = blockIdx.x * blockDim.x + threadIdx.x;
    if (i < n) deg[i] = rsqrtf(deg[i]);
}

__global__ __launch_bounds__(256) void compute_norm(const int* __restrict__ src,
                                                    const int* __restrict__ dst,
                                                    const float* __restrict__ dinv,
                                                    float* __restrict__ norm, int e) {
    int i = blockIdx.x * blockDim.x + threadIdx.x;
    if (i < e) norm[i] = dinv[src[i]] * dinv[dst[i]];
}

// ---------------- dense GEMM: Y[N,COUT] = X[N,K] @ W[K,COUT] ----------------
// Block: 256 threads handles 16 rows. W fully staged in LDS (max 32 KB),
// X tile (16 rows) in LDS. Thread t computes col (t&63) for rows (t>>6)+4i.

template <int K, int COUT>
__global__ __launch_bounds__(256) void gemm_kernel(const float* __restrict__ X,
                                                   const float* __restrict__ W,
                                                   float* __restrict__ Y) {
    __shared__ float Wl[K * COUT];
    __shared__ float Xl[16 * K];
    const int t = threadIdx.x;
    const int row0 = blockIdx.x * 16;

    for (int i = t; i < K * COUT; i += 256) Wl[i] = W[i];
    for (int i = t; i < 16 * K; i += 256) Xl[i] = X[row0 * K + i];
    __syncthreads();

    const int c = t & 63;
    const int rs = t >> 6;
    if (c < COUT) {
        float acc[4] = {0.f, 0.f, 0.f, 0.f};
#pragma unroll 8
        for (int k = 0; k < K; ++k) {
            float w = Wl[k * COUT + c];
#pragma unroll
            for (int i = 0; i < 4; ++i) acc[i] += Xl[(rs + 4 * i) * K + k] * w;
        }
#pragma unroll
        for (int i = 0; i < 4; ++i) Y[(row0 + rs + 4 * i) * COUT + c] = acc[i];
    }
}

// ---------------- aggregation ----------------
// agg[i,c] = bias[c] + dinv[i]^2 * tmp[i,c]   (self-loop term + bias, also inits buffer)

template <int COUT>
__global__ __launch_bounds__(256) void init_agg(const float* __restrict__ tmp,
                                                const float* __restrict__ dinv,
                                                const float* __restrict__ bias,
                                                float* __restrict__ agg, int n) {
    int gid = blockIdx.x * blockDim.x + threadIdx.x;
    int total = n * COUT;
    if (gid < total) {
        int node = gid / COUT;
        int c = gid - node * COUT;
        float di = dinv[node];
        agg[gid] = bias[c] + di * di * tmp[gid];
    }
}

// agg[dst,c] += norm[e] * tmp[src,c]  — one thread per (edge, 4-channel group)

template <int COUT>
__global__ __launch_bounds__(256) void scatter_edges(const int* __restrict__ src,
                                                     const int* __restrict__ dst,
                                                     const float* __restrict__ norm,
                                                     const float* __restrict__ tmp,
                                                     float* agg, int e) {
    constexpr int Q = COUT / 4;
    int gid = blockIdx.x * blockDim.x + threadIdx.x;
    int ed = gid / Q;
    int q = gid - ed * Q;
    if (ed < e) {
        int s = src[ed], d = dst[ed];
        float w = norm[ed];
        float4 v = ((const float4*)tmp)[s * Q + q];
        float* base = agg + d * COUT + q * 4;
        atomicAdd(base + 0, w * v.x);
        atomicAdd(base + 1, w * v.y);
        atomicAdd(base + 2, w * v.z);
        atomicAdd(base + 3, w * v.w);
    }
}

__global__ __launch_bounds__(256) void relu_kernel(float* h, int total) {
    int i = blockIdx.x * blockDim.x + threadIdx.x;
    if (i < total) h[i] = fmaxf(h[i], 0.f);
}

// ---------------- launch ----------------

extern "C" void kernel_launch(void* const* d_in, const int* in_sizes, int n_in,
                              void* d_out, int out_size, void* d_ws, size_t ws_size,
                              hipStream_t stream) {
    const float* x  = (const float*)d_in[0];
    const int*   ei = (const int*)d_in[1];
    const int*   src = ei;
    const int*   dst = ei + N_EDGES;
    const float* W1 = (const float*)d_in[2];
    const float* b1 = (const float*)d_in[3];
    const float* W2 = (const float*)d_in[4];
    const float* b2 = (const float*)d_in[5];
    const float* W3 = (const float*)d_in[6];
    const float* b3 = (const float*)d_in[7];
    float* out = (float*)d_out;

    float* ws   = (float*)d_ws;
    float* dinv = ws;                       // N
    float* norm = dinv + N_NODES;           // E   (N_NODES % 4 == 0 keeps 16B alignment)
    float* bufA = norm + N_EDGES;           // N*64
    float* bufB = bufA + N_NODES * 64;      // N*64

    const int N = N_NODES, E = N_EDGES;

    // degree / norm
    init_deg<<<(N + 255) / 256, 256, 0, stream>>>(dinv, N);
    accum_deg<<<(E + 255) / 256, 256, 0, stream>>>(dst, dinv, E);
    deg_to_dinv<<<(N + 255) / 256, 256, 0, stream>>>(dinv, N);
    compute_norm<<<(E + 255) / 256, 256, 0, stream>>>(src, dst, dinv, norm, E);

    // layer 1: x[N,128] @ W1 -> bufA[N,64]; aggregate -> bufB; relu
    gemm_kernel<128, 64><<<N / 16, 256, 0, stream>>>(x, W1, bufA);
    init_agg<64><<<(N * 64 + 255) / 256, 256, 0, stream>>>(bufA, dinv, b1, bufB, N);
    scatter_edges<64><<<(E * 16 + 255) / 256, 256, 0, stream>>>(src, dst, norm, bufA, bufB, E);
    relu_kernel<<<(N * 64 + 255) / 256, 256, 0, stream>>>(bufB, N * 64);

    // layer 2: bufB[N,64] @ W2 -> bufA[N,64]; aggregate -> bufB; relu
    gemm_kernel<64, 64><<<N / 16, 256, 0, stream>>>(bufB, W2, bufA);
    init_agg<64><<<(N * 64 + 255) / 256, 256, 0, stream>>>(bufA, dinv, b2, bufB, N);
    scatter_edges<64><<<(E * 16 + 255) / 256, 256, 0, stream>>>(src, dst, norm, bufA, bufB, E);
    relu_kernel<<<(N * 64 + 255) / 256, 256, 0, stream>>>(bufB, N * 64);

    // layer 3: bufB[N,64] @ W3 -> bufA[N,40]; aggregate -> out (no relu)
    gemm_kernel<64, 40><<<N / 16, 256, 0, stream>>>(bufB, W3, bufA);
    init_agg<40><<<(N * 40 + 255) / 256, 256, 0, stream>>>(bufA, dinv, b3, out, N);
    scatter_edges<40><<<(E * 10 + 255) / 256, 256, 0, stream>>>(src, dst, norm, bufA, out, E);
}

// Round 2
// 859.790 us; speedup vs baseline: 4.5753x; 4.5753x over previous
//
#include <hip/hip_runtime.h>

#define N_NODES 100000
#define N_EDGES 1600000
#define SCAN_BLOCK 256
#define N_BLOCKS ((N_NODES + SCAN_BLOCK - 1) / SCAN_BLOCK)  // 391

// ---------------- CSR build: histogram -> scan -> fill ----------------

__global__ __launch_bounds__(256) void zero_counts(int* counts, int n) {
    int i = blockIdx.x * blockDim.x + threadIdx.x;
    if (i < n) counts[i] = 0;
}

__global__ __launch_bounds__(256) void hist_deg(const int* __restrict__ dst, int* counts, int e) {
    int i = blockIdx.x * blockDim.x + threadIdx.x;
    if (i < e) atomicAdd(&counts[dst[i]], 1);
}

// dinv[i] = rsqrt(deg_with_selfloop)
__global__ __launch_bounds__(256) void counts_to_dinv(const int* __restrict__ counts,
                                                      float* __restrict__ dinv, int n) {
    int i = blockIdx.x * blockDim.x + threadIdx.x;
    if (i < n) dinv[i] = rsqrtf((float)(counts[i] + 1));
}

__global__ __launch_bounds__(SCAN_BLOCK) void block_sums(const int* __restrict__ counts,
                                                         int* __restrict__ bsum, int n) {
    __shared__ int sm[SCAN_BLOCK];
    int i = blockIdx.x * SCAN_BLOCK + threadIdx.x;
    sm[threadIdx.x] = (i < n) ? counts[i] : 0;
    __syncthreads();
    for (int s = SCAN_BLOCK / 2; s > 0; s >>= 1) {
        if (threadIdx.x < s) sm[threadIdx.x] += sm[threadIdx.x + s];
        __syncthreads();
    }
    if (threadIdx.x == 0) bsum[blockIdx.x] = sm[0];
}

// single-thread exclusive scan of ~391 block sums (trivial cost)
__global__ void scan_bsums(int* bsum, int nb) {
    int acc = 0;
    for (int i = 0; i < nb; ++i) { int v = bsum[i]; bsum[i] = acc; acc += v; }
}

__global__ __launch_bounds__(SCAN_BLOCK) void make_row_ptr(const int* __restrict__ counts,
                                                           const int* __restrict__ bsum,
                                                           int* __restrict__ row_ptr,
                                                           int* __restrict__ cursor, int n, int e) {
    __shared__ int sm[SCAN_BLOCK];
    int i = blockIdx.x * SCAN_BLOCK + threadIdx.x;
    sm[threadIdx.x] = (i < n) ? counts[i] : 0;
    __syncthreads();
    // simple O(B) per-thread exclusive prefix within the block (B=256; cheap)
    int pre = 0;
    for (int j = 0; j < (int)threadIdx.x; ++j) pre += sm[j];
    if (i < n) {
        int rp = bsum[blockIdx.x] + pre;
        row_ptr[i] = rp;
        cursor[i] = rp;
    }
    if (i == n - 1) row_ptr[n] = e;
}

__global__ __launch_bounds__(256) void fill_csr(const int* __restrict__ src,
                                                const int* __restrict__ dst,
                                                const float* __restrict__ dinv,
                                                int* cursor,
                                                int* __restrict__ csr_src,
                                                float* __restrict__ csr_norm, int e) {
    int i = blockIdx.x * blockDim.x + threadIdx.x;
    if (i < e) {
        int s = src[i], d = dst[i];
        int pos = atomicAdd(&cursor[d], 1);
        csr_src[pos] = s;
        csr_norm[pos] = dinv[s] * dinv[d];
    }
}

// ---------------- dense GEMM: Y[N,COUT] = X[N,K] @ W[K,COUT] ----------------

template <int K, int COUT>
__global__ __launch_bounds__(256) void gemm_kernel(const float* __restrict__ X,
                                                   const float* __restrict__ W,
                                                   float* __restrict__ Y) {
    __shared__ float Wl[K * COUT];
    __shared__ float Xl[16 * K];
    const int t = threadIdx.x;
    const int row0 = blockIdx.x * 16;

    for (int i = t; i < K * COUT; i += 256) Wl[i] = W[i];
    for (int i = t; i < 16 * K; i += 256) Xl[i] = X[row0 * K + i];
    __syncthreads();

    const int c = t & 63;
    const int rs = t >> 6;
    if (c < COUT) {
        float acc[4] = {0.f, 0.f, 0.f, 0.f};
#pragma unroll 8
        for (int k = 0; k < K; ++k) {
            float w = Wl[k * COUT + c];
#pragma unroll
            for (int i = 0; i < 4; ++i) acc[i] += Xl[(rs + 4 * i) * K + k] * w;
        }
#pragma unroll
        for (int i = 0; i < 4; ++i) Y[(row0 + rs + 4 * i) * COUT + c] = acc[i];
    }
}

// ---------------- fused aggregation: CSR gather + self-loop + bias (+ReLU) ----------------
// One 64-lane wave per dst node; lane = channel. Per edge: coalesced COUT*4B row read.

template <int COUT, bool RELU>
__global__ __launch_bounds__(256) void aggregate(const float* __restrict__ tmp,
                                                 const int* __restrict__ row_ptr,
                                                 const int* __restrict__ csr_src,
                                                 const float* __restrict__ csr_norm,
                                                 const float* __restrict__ dinv,
                                                 const float* __restrict__ bias,
                                                 float* __restrict__ out, int n) {
    const int lane = threadIdx.x & 63;
    const int node = blockIdx.x * 4 + (threadIdx.x >> 6);
    if (node >= n) return;

    const int beg = row_ptr[node];
    const int end = row_ptr[node + 1];
    float acc = 0.0f;
    if (lane < COUT) {
        for (int j = beg; j < end; ++j) {
            int s = csr_src[j];
            float w = csr_norm[j];
            acc += w * tmp[s * COUT + lane];
        }
        float di = dinv[node];
        float v = bias[lane] + di * di * tmp[node * COUT + lane] + acc;
        if (RELU) v = fmaxf(v, 0.0f);
        out[node * COUT + lane] = v;
    }
}

// ---------------- launch ----------------

extern "C" void kernel_launch(void* const* d_in, const int* in_sizes, int n_in,
                              void* d_out, int out_size, void* d_ws, size_t ws_size,
                              hipStream_t stream) {
    const float* x  = (const float*)d_in[0];
    const int*   ei = (const int*)d_in[1];
    const int*   src = ei;
    const int*   dst = ei + N_EDGES;
    const float* W1 = (const float*)d_in[2];
    const float* b1 = (const float*)d_in[3];
    const float* W2 = (const float*)d_in[4];
    const float* b2 = (const float*)d_in[5];
    const float* W3 = (const float*)d_in[6];
    const float* b3 = (const float*)d_in[7];
    float* out = (float*)d_out;

    const int N = N_NODES, E = N_EDGES;

    // workspace carve-up (all 4B-typed; keep 16B alignment via multiples of 4)
    char* p = (char*)d_ws;
    int*   counts   = (int*)p;              p += (size_t)N * 4;
    float* dinv     = (float*)p;            p += (size_t)N * 4;
    int*   row_ptr  = (int*)p;              p += (size_t)(N + 4) * 4;
    int*   cursor   = (int*)p;              p += (size_t)N * 4;
    int*   bsum     = (int*)p;              p += (size_t)(N_BLOCKS + 1) * 4;
    int*   csr_src  = (int*)p;              p += (size_t)E * 4;
    float* csr_norm = (float*)p;            p += (size_t)E * 4;
    float* bufA     = (float*)p;            p += (size_t)N * 64 * 4;
    float* bufB     = (float*)p;            p += (size_t)N * 64 * 4;

    // ---- CSR build (reused by all 3 layers) ----
    zero_counts<<<(N + 255) / 256, 256, 0, stream>>>(counts, N);
    hist_deg<<<(E + 255) / 256, 256, 0, stream>>>(dst, counts, E);
    counts_to_dinv<<<(N + 255) / 256, 256, 0, stream>>>(counts, dinv, N);
    block_sums<<<N_BLOCKS, SCAN_BLOCK, 0, stream>>>(counts, bsum, N);
    scan_bsums<<<1, 1, 0, stream>>>(bsum, N_BLOCKS);
    make_row_ptr<<<N_BLOCKS, SCAN_BLOCK, 0, stream>>>(counts, bsum, row_ptr, cursor, N, E);
    fill_csr<<<(E + 255) / 256, 256, 0, stream>>>(src, dst, dinv, cursor, csr_src, csr_norm, E);

    const int aggGrid = (N + 3) / 4;

    // layer 1: x[N,128] @ W1 -> bufA[N,64]; aggregate+relu -> bufB
    gemm_kernel<128, 64><<<N / 16, 256, 0, stream>>>(x, W1, bufA);
    aggregate<64, true><<<aggGrid, 256, 0, stream>>>(bufA, row_ptr, csr_src, csr_norm,
                                                     dinv, b1, bufB, N);

    // layer 2: bufB[N,64] @ W2 -> bufA[N,64]; aggregate+relu -> bufB
    gemm_kernel<64, 64><<<N / 16, 256, 0, stream>>>(bufB, W2, bufA);
    aggregate<64, true><<<aggGrid, 256, 0, stream>>>(bufA, row_ptr, csr_src, csr_norm,
                                                     dinv, b2, bufB, N);

    // layer 3: bufB[N,64] @ W3 -> bufA[N,40]; aggregate -> out (no relu)
    gemm_kernel<64, 40><<<N / 16, 256, 0, stream>>>(bufB, W3, bufA);
    aggregate<40, false><<<aggGrid, 256, 0, stream>>>(bufA, row_ptr, csr_src, csr_norm,
                                                      dinv, b3, out, N);
}

// Round 3
// 646.432 us; speedup vs baseline: 6.0854x; 1.3301x over previous
//
#include <hip/hip_runtime.h>

#define N_NODES 100000
#define N_EDGES 1600000
#define SCAN_BLOCK 256
#define N_BLOCKS ((N_NODES + SCAN_BLOCK - 1) / SCAN_BLOCK)  // 391

// ---------------- CSR build: histogram -> scan -> fill ----------------

__global__ __launch_bounds__(256) void zero_counts(int* counts, int n) {
    int i = blockIdx.x * blockDim.x + threadIdx.x;
    if (i < n) counts[i] = 0;
}

__global__ __launch_bounds__(256) void hist_deg(const int* __restrict__ dst, int* counts, int e) {
    int i = blockIdx.x * blockDim.x + threadIdx.x;
    if (i < e) atomicAdd(&counts[dst[i]], 1);
}

// dinv[i] = rsqrt(deg_with_selfloop)
__global__ __launch_bounds__(256) void counts_to_dinv(const int* __restrict__ counts,
                                                      float* __restrict__ dinv, int n) {
    int i = blockIdx.x * blockDim.x + threadIdx.x;
    if (i < n) dinv[i] = rsqrtf((float)(counts[i] + 1));
}

__global__ __launch_bounds__(SCAN_BLOCK) void block_sums(const int* __restrict__ counts,
                                                         int* __restrict__ bsum, int n) {
    __shared__ int sm[SCAN_BLOCK];
    int i = blockIdx.x * SCAN_BLOCK + threadIdx.x;
    sm[threadIdx.x] = (i < n) ? counts[i] : 0;
    __syncthreads();
    for (int s = SCAN_BLOCK / 2; s > 0; s >>= 1) {
        if (threadIdx.x < s) sm[threadIdx.x] += sm[threadIdx.x + s];
        __syncthreads();
    }
    if (threadIdx.x == 0) bsum[blockIdx.x] = sm[0];
}

__global__ void scan_bsums(int* bsum, int nb) {
    int acc = 0;
    for (int i = 0; i < nb; ++i) { int v = bsum[i]; bsum[i] = acc; acc += v; }
}

__global__ __launch_bounds__(SCAN_BLOCK) void make_row_ptr(const int* __restrict__ counts,
                                                           const int* __restrict__ bsum,
                                                           int* __restrict__ row_ptr,
                                                           int* __restrict__ cursor, int n, int e) {
    __shared__ int sm[SCAN_BLOCK];
    int i = blockIdx.x * SCAN_BLOCK + threadIdx.x;
    sm[threadIdx.x] = (i < n) ? counts[i] : 0;
    __syncthreads();
    int pre = 0;
    for (int j = 0; j < (int)threadIdx.x; ++j) pre += sm[j];
    if (i < n) {
        int rp = bsum[blockIdx.x] + pre;
        row_ptr[i] = rp;
        cursor[i] = rp;
    }
    if (i == n - 1) row_ptr[n] = e;
}

__global__ __launch_bounds__(256) void fill_csr(const int* __restrict__ src,
                                                const int* __restrict__ dst,
                                                int* cursor,
                                                int* __restrict__ csr_src, int e) {
    int i = blockIdx.x * blockDim.x + threadIdx.x;
    if (i < e) {
        int d = dst[i];
        int pos = atomicAdd(&cursor[d], 1);
        csr_src[pos] = src[i];
    }
}

// ---------------- dense GEMM: Y[N,COUT] = dinv[row] * (X[N,K] @ W[K,COUT]) ----------------

template <int K, int COUT>
__global__ __launch_bounds__(256) void gemm_kernel(const float* __restrict__ X,
                                                   const float* __restrict__ W,
                                                   const float* __restrict__ dinv,
                                                   float* __restrict__ Y) {
    __shared__ float Wl[K * COUT];
    __shared__ float Xl[16 * K];
    const int t = threadIdx.x;
    const int row0 = blockIdx.x * 16;

    for (int i = t; i < K * COUT; i += 256) Wl[i] = W[i];
    for (int i = t; i < 16 * K; i += 256) Xl[i] = X[row0 * K + i];
    __syncthreads();

    const int c = t & 63;
    const int rs = t >> 6;
    if (c < COUT) {
        float acc[4] = {0.f, 0.f, 0.f, 0.f};
#pragma unroll 8
        for (int k = 0; k < K; ++k) {
            float w = Wl[k * COUT + c];
#pragma unroll
            for (int i = 0; i < 4; ++i) acc[i] += Xl[(rs + 4 * i) * K + k] * w;
        }
#pragma unroll
        for (int i = 0; i < 4; ++i) {
            int row = row0 + rs + 4 * i;
            Y[row * COUT + c] = dinv[row] * acc[i];
        }
    }
}

// ---------------- fused aggregation ----------------
// tS[i] = dinv[i] * (h@W)[i] (from gemm). out[d] = bias + dinv[d]*(tS[d] + sum_j tS[src_j]).
// One 64-lane wave per dst node; lane = channel. Edge indices preloaded lane-parallel,
// broadcast by shfl; unroll-4 independent accumulators for memory-level parallelism.

template <int COUT, bool RELU>
__global__ __launch_bounds__(256) void aggregate(const float* __restrict__ tS,
                                                 const int* __restrict__ row_ptr,
                                                 const int* __restrict__ csr_src,
                                                 const float* __restrict__ dinv,
                                                 const float* __restrict__ bias,
                                                 float* __restrict__ out, int n) {
    const int lane = threadIdx.x & 63;
    const int node = blockIdx.x * 4 + (threadIdx.x >> 6);
    if (node >= n) return;

    const int beg = row_ptr[node];
    const int cnt = row_ptr[node + 1] - beg;

    float acc0 = 0.f, acc1 = 0.f, acc2 = 0.f, acc3 = 0.f;

    for (int j0 = 0; j0 < cnt; j0 += 64) {
        const int m = min(64, cnt - j0);
        // lane-parallel coalesced preload of edge sources
        int sj = (lane < m) ? csr_src[beg + j0 + lane] : 0;

        int j = 0;
        for (; j + 4 <= m; j += 4) {
            int s0 = __shfl(sj, j + 0);
            int s1 = __shfl(sj, j + 1);
            int s2 = __shfl(sj, j + 2);
            int s3 = __shfl(sj, j + 3);
            if (lane < COUT) {
                float v0 = tS[(size_t)s0 * COUT + lane];
                float v1 = tS[(size_t)s1 * COUT + lane];
                float v2 = tS[(size_t)s2 * COUT + lane];
                float v3 = tS[(size_t)s3 * COUT + lane];
                acc0 += v0; acc1 += v1; acc2 += v2; acc3 += v3;
            }
        }
        for (; j < m; ++j) {
            int s = __shfl(sj, j);
            if (lane < COUT) acc0 += tS[(size_t)s * COUT + lane];
        }
    }

    if (lane < COUT) {
        float sum = (acc0 + acc1) + (acc2 + acc3) + tS[(size_t)node * COUT + lane];
        float v = bias[lane] + dinv[node] * sum;
        if (RELU) v = fmaxf(v, 0.0f);
        out[(size_t)node * COUT + lane] = v;
    }
}

// ---------------- launch ----------------

extern "C" void kernel_launch(void* const* d_in, const int* in_sizes, int n_in,
                              void* d_out, int out_size, void* d_ws, size_t ws_size,
                              hipStream_t stream) {
    const float* x  = (const float*)d_in[0];
    const int*   ei = (const int*)d_in[1];
    const int*   src = ei;
    const int*   dst = ei + N_EDGES;
    const float* W1 = (const float*)d_in[2];
    const float* b1 = (const float*)d_in[3];
    const float* W2 = (const float*)d_in[4];
    const float* b2 = (const float*)d_in[5];
    const float* W3 = (const float*)d_in[6];
    const float* b3 = (const float*)d_in[7];
    float* out = (float*)d_out;

    const int N = N_NODES, E = N_EDGES;

    char* p = (char*)d_ws;
    int*   counts   = (int*)p;              p += (size_t)N * 4;
    float* dinv     = (float*)p;            p += (size_t)N * 4;
    int*   row_ptr  = (int*)p;              p += (size_t)(N + 4) * 4;
    int*   cursor   = (int*)p;              p += (size_t)N * 4;
    int*   bsum     = (int*)p;              p += (size_t)(N_BLOCKS + 1) * 4;
    int*   csr_src  = (int*)p;              p += (size_t)E * 4;
    float* bufA     = (float*)p;            p += (size_t)N * 64 * 4;
    float* bufB     = (float*)p;            p += (size_t)N * 64 * 4;

    // ---- CSR build (reused by all 3 layers) ----
    zero_counts<<<(N + 255) / 256, 256, 0, stream>>>(counts, N);
    hist_deg<<<(E + 255) / 256, 256, 0, stream>>>(dst, counts, E);
    counts_to_dinv<<<(N + 255) / 256, 256, 0, stream>>>(counts, dinv, N);
    block_sums<<<N_BLOCKS, SCAN_BLOCK, 0, stream>>>(counts, bsum, N);
    scan_bsums<<<1, 1, 0, stream>>>(bsum, N_BLOCKS);
    make_row_ptr<<<N_BLOCKS, SCAN_BLOCK, 0, stream>>>(counts, bsum, row_ptr, cursor, N, E);
    fill_csr<<<(E + 255) / 256, 256, 0, stream>>>(src, dst, cursor, csr_src, E);

    const int aggGrid = (N + 3) / 4;

    // layer 1
    gemm_kernel<128, 64><<<N / 16, 256, 0, stream>>>(x, W1, dinv, bufA);
    aggregate<64, true><<<aggGrid, 256, 0, stream>>>(bufA, row_ptr, csr_src, dinv, b1, bufB, N);

    // layer 2
    gemm_kernel<64, 64><<<N / 16, 256, 0, stream>>>(bufB, W2, dinv, bufA);
    aggregate<64, true><<<aggGrid, 256, 0, stream>>>(bufA, row_ptr, csr_src, dinv, b2, bufB, N);

    // layer 3
    gemm_kernel<64, 40><<<N / 16, 256, 0, stream>>>(bufB, W3, dinv, bufA);
    aggregate<40, false><<<aggGrid, 256, 0, stream>>>(bufA, row_ptr, csr_src, dinv, b3, out, N);
}

// Round 4
// 624.155 us; speedup vs baseline: 6.3026x; 1.0357x over previous
//
#include <hip/hip_runtime.h>

#define N_NODES 100000
#define N_EDGES 1600000
#define SCAN_BLOCK 256
#define N_BLOCKS ((N_NODES + SCAN_BLOCK - 1) / SCAN_BLOCK)  // 391

// ---------------- CSR build: histogram -> scan -> fill ----------------

__global__ __launch_bounds__(256) void zero_counts(int* counts, int n) {
    int i = blockIdx.x * blockDim.x + threadIdx.x;
    if (i < n) counts[i] = 0;
}

__global__ __launch_bounds__(256) void hist_deg(const int* __restrict__ dst, int* counts, int e) {
    int i = blockIdx.x * blockDim.x + threadIdx.x;
    if (i < e) atomicAdd(&counts[dst[i]], 1);
}

__global__ __launch_bounds__(256) void counts_to_dinv(const int* __restrict__ counts,
                                                      float* __restrict__ dinv, int n) {
    int i = blockIdx.x * blockDim.x + threadIdx.x;
    if (i < n) dinv[i] = rsqrtf((float)(counts[i] + 1));
}

__global__ __launch_bounds__(SCAN_BLOCK) void block_sums(const int* __restrict__ counts,
                                                         int* __restrict__ bsum, int n) {
    __shared__ int sm[SCAN_BLOCK];
    int i = blockIdx.x * SCAN_BLOCK + threadIdx.x;
    sm[threadIdx.x] = (i < n) ? counts[i] : 0;
    __syncthreads();
    for (int s = SCAN_BLOCK / 2; s > 0; s >>= 1) {
        if (threadIdx.x < s) sm[threadIdx.x] += sm[threadIdx.x + s];
        __syncthreads();
    }
    if (threadIdx.x == 0) bsum[blockIdx.x] = sm[0];
}

__global__ void scan_bsums(int* bsum, int nb) {
    int acc = 0;
    for (int i = 0; i < nb; ++i) { int v = bsum[i]; bsum[i] = acc; acc += v; }
}

__global__ __launch_bounds__(SCAN_BLOCK) void make_row_ptr(const int* __restrict__ counts,
                                                           const int* __restrict__ bsum,
                                                           int* __restrict__ row_ptr,
                                                           int* __restrict__ cursor, int n, int e) {
    __shared__ int sm[SCAN_BLOCK];
    int i = blockIdx.x * SCAN_BLOCK + threadIdx.x;
    sm[threadIdx.x] = (i < n) ? counts[i] : 0;
    __syncthreads();
    int pre = 0;
    for (int j = 0; j < (int)threadIdx.x; ++j) pre += sm[j];
    if (i < n) {
        int rp = bsum[blockIdx.x] + pre;
        row_ptr[i] = rp;
        cursor[i] = rp;
    }
    if (i == n - 1) row_ptr[n] = e;
}

__global__ __launch_bounds__(256) void fill_csr(const int* __restrict__ src,
                                                const int* __restrict__ dst,
                                                int* cursor,
                                                int* __restrict__ csr_src, int e) {
    int i = blockIdx.x * blockDim.x + threadIdx.x;
    if (i < e) {
        int d = dst[i];
        int pos = atomicAdd(&cursor[d], 1);
        __builtin_nontemporal_store(src[i], &csr_src[pos]);
    }
}

// ---------------- register-tiled GEMM: Y = dinv[row] * (X[N,K] @ W[K,COUT]) ----------------
// 64x64 output tile per 256-thread block; thread owns 4 rows x 4 cols (16 acc).
// K staged in 64-wide chunks: Xl[64][68] (pad +4 -> only 2-way bank alias, free),
// Wl[64][COUT]. Per k: 4x ds_read_b32 + 1x ds_read_b128 feed 16 v_fma.

template <int K, int COUT>
__global__ __launch_bounds__(256) void gemm_rt(const float* __restrict__ X,
                                               const float* __restrict__ W,
                                               const float* __restrict__ dinv,
                                               float* __restrict__ Y, int n) {
    constexpr int KC = 64;
    constexpr int S = KC + 4;
    constexpr int NCHUNK = K / KC;
    __shared__ float Xl[64 * S];
    __shared__ float Wl[KC * COUT];

    const int t = threadIdx.x;
    const int row0 = blockIdx.x * 64;
    const int cg = (t & 15) * 4;   // col base
    const int rg = (t >> 4) * 4;   // row base

    float acc[4][4] = {};

#pragma unroll
    for (int ch = 0; ch < NCHUNK; ++ch) {
        const int k0 = ch * KC;
        // stage X chunk (rows row0..+63, cols k0..+63), coalesced float4
        for (int i = t; i < 64 * KC / 4; i += 256) {
            int r = i >> 4;
            int k = (i & 15) * 4;
            int grow = row0 + r;
            if (grow >= n) grow = n - 1;
            float4 v = *(const float4*)(X + (size_t)grow * K + k0 + k);
            *(float4*)(Xl + r * S + k) = v;
        }
        // stage W chunk, contiguous float4
        for (int i = t; i < KC * COUT / 4; i += 256) {
            float4 v = *(const float4*)(W + (size_t)k0 * COUT + (size_t)i * 4);
            *(float4*)(Wl + i * 4) = v;
        }
        __syncthreads();

        if (cg < COUT) {
#pragma unroll 4
            for (int k = 0; k < KC; ++k) {
                float4 w = *(const float4*)(Wl + k * COUT + cg);
                float x0 = Xl[(rg + 0) * S + k];
                float x1 = Xl[(rg + 1) * S + k];
                float x2 = Xl[(rg + 2) * S + k];
                float x3 = Xl[(rg + 3) * S + k];
                acc[0][0] += x0 * w.x; acc[0][1] += x0 * w.y; acc[0][2] += x0 * w.z; acc[0][3] += x0 * w.w;
                acc[1][0] += x1 * w.x; acc[1][1] += x1 * w.y; acc[1][2] += x1 * w.z; acc[1][3] += x1 * w.w;
                acc[2][0] += x2 * w.x; acc[2][1] += x2 * w.y; acc[2][2] += x2 * w.z; acc[2][3] += x2 * w.w;
                acc[3][0] += x3 * w.x; acc[3][1] += x3 * w.y; acc[3][2] += x3 * w.z; acc[3][3] += x3 * w.w;
            }
        }
        __syncthreads();
    }

    if (cg < COUT) {
#pragma unroll
        for (int r = 0; r < 4; ++r) {
            int row = row0 + rg + r;
            if (row < n) {
                float d = dinv[row];
                float4 o = { d * acc[r][0], d * acc[r][1], d * acc[r][2], d * acc[r][3] };
                *(float4*)(Y + (size_t)row * COUT + cg) = o;
            }
        }
    }
}

// ---------------- fused aggregation ----------------
// tS[i] = dinv[i]*(h@W)[i]. out[d] = bias + dinv[d]*(tS[d] + sum_j tS[src_j]).
// One wave per dst node; lane = channel. 64 edge ids preloaded lane-parallel,
// broadcast by shfl; unroll-8 independent accumulators for MLP.

template <int COUT, bool RELU>
__global__ __launch_bounds__(256) void aggregate(const float* __restrict__ tS,
                                                 const int* __restrict__ row_ptr,
                                                 const int* __restrict__ csr_src,
                                                 const float* __restrict__ dinv,
                                                 const float* __restrict__ bias,
                                                 float* __restrict__ out, int n) {
    const int lane = threadIdx.x & 63;
    const int node = blockIdx.x * 4 + (threadIdx.x >> 6);
    if (node >= n) return;

    const int beg = row_ptr[node];
    const int cnt = row_ptr[node + 1] - beg;

    float acc[8] = {};

    for (int j0 = 0; j0 < cnt; j0 += 64) {
        const int m = min(64, cnt - j0);
        int sj = (lane < m) ? csr_src[beg + j0 + lane] : 0;

        int j = 0;
        for (; j + 8 <= m; j += 8) {
            int s0 = __shfl(sj, j + 0);
            int s1 = __shfl(sj, j + 1);
            int s2 = __shfl(sj, j + 2);
            int s3 = __shfl(sj, j + 3);
            int s4 = __shfl(sj, j + 4);
            int s5 = __shfl(sj, j + 5);
            int s6 = __shfl(sj, j + 6);
            int s7 = __shfl(sj, j + 7);
            if (lane < COUT) {
                acc[0] += tS[(size_t)s0 * COUT + lane];
                acc[1] += tS[(size_t)s1 * COUT + lane];
                acc[2] += tS[(size_t)s2 * COUT + lane];
                acc[3] += tS[(size_t)s3 * COUT + lane];
                acc[4] += tS[(size_t)s4 * COUT + lane];
                acc[5] += tS[(size_t)s5 * COUT + lane];
                acc[6] += tS[(size_t)s6 * COUT + lane];
                acc[7] += tS[(size_t)s7 * COUT + lane];
            }
        }
        for (; j < m; ++j) {
            int s = __shfl(sj, j);
            if (lane < COUT) acc[0] += tS[(size_t)s * COUT + lane];
        }
    }

    if (lane < COUT) {
        float sum = ((acc[0] + acc[1]) + (acc[2] + acc[3])) +
                    ((acc[4] + acc[5]) + (acc[6] + acc[7])) +
                    tS[(size_t)node * COUT + lane];
        float v = bias[lane] + dinv[node] * sum;
        if (RELU) v = fmaxf(v, 0.0f);
        out[(size_t)node * COUT + lane] = v;
    }
}

// ---------------- launch ----------------

extern "C" void kernel_launch(void* const* d_in, const int* in_sizes, int n_in,
                              void* d_out, int out_size, void* d_ws, size_t ws_size,
                              hipStream_t stream) {
    const float* x  = (const float*)d_in[0];
    const int*   ei = (const int*)d_in[1];
    const int*   src = ei;
    const int*   dst = ei + N_EDGES;
    const float* W1 = (const float*)d_in[2];
    const float* b1 = (const float*)d_in[3];
    const float* W2 = (const float*)d_in[4];
    const float* b2 = (const float*)d_in[5];
    const float* W3 = (const float*)d_in[6];
    const float* b3 = (const float*)d_in[7];
    float* out = (float*)d_out;

    const int N = N_NODES, E = N_EDGES;

    char* p = (char*)d_ws;
    int*   counts   = (int*)p;              p += (size_t)N * 4;
    float* dinv     = (float*)p;            p += (size_t)N * 4;
    int*   row_ptr  = (int*)p;              p += (size_t)(N + 4) * 4;
    int*   cursor   = (int*)p;              p += (size_t)N * 4;
    int*   bsum     = (int*)p;              p += (size_t)(N_BLOCKS + 1) * 4;
    int*   csr_src  = (int*)p;              p += (size_t)E * 4;
    float* bufA     = (float*)p;            p += (size_t)N * 64 * 4;
    float* bufB     = (float*)p;            p += (size_t)N * 64 * 4;

    // ---- CSR build (reused by all 3 layers) ----
    zero_counts<<<(N + 255) / 256, 256, 0, stream>>>(counts, N);
    hist_deg<<<(E + 255) / 256, 256, 0, stream>>>(dst, counts, E);
    counts_to_dinv<<<(N + 255) / 256, 256, 0, stream>>>(counts, dinv, N);
    block_sums<<<N_BLOCKS, SCAN_BLOCK, 0, stream>>>(counts, bsum, N);
    scan_bsums<<<1, 1, 0, stream>>>(bsum, N_BLOCKS);
    make_row_ptr<<<N_BLOCKS, SCAN_BLOCK, 0, stream>>>(counts, bsum, row_ptr, cursor, N, E);
    fill_csr<<<(E + 255) / 256, 256, 0, stream>>>(src, dst, cursor, csr_src, E);

    const int aggGrid = (N + 3) / 4;
    const int gemmGrid = (N + 63) / 64;

    // layer 1
    gemm_rt<128, 64><<<gemmGrid, 256, 0, stream>>>(x, W1, dinv, bufA, N);
    aggregate<64, true><<<aggGrid, 256, 0, stream>>>(bufA, row_ptr, csr_src, dinv, b1, bufB, N);

    // layer 2
    gemm_rt<64, 64><<<gemmGrid, 256, 0, stream>>>(bufB, W2, dinv, bufA, N);
    aggregate<64, true><<<aggGrid, 256, 0, stream>>>(bufA, row_ptr, csr_src, dinv, b2, bufB, N);

    // layer 3
    gemm_rt<64, 40><<<gemmGrid, 256, 0, stream>>>(bufB, W3, dinv, bufA, N);
    aggregate<40, false><<<aggGrid, 256, 0, stream>>>(bufA, row_ptr, csr_src, dinv, b3, out, N);
}

// Round 5
// 529.952 us; speedup vs baseline: 7.4229x; 1.1778x over previous
//
#include <hip/hip_runtime.h>

#define N_NODES 100000
#define N_EDGES 1600000
#define SCAN_BLOCK 256
#define N_BLOCKS ((N_NODES + SCAN_BLOCK - 1) / SCAN_BLOCK)  // 391
#define NRANGE 8
#define RANGE_SZ (N_NODES / NRANGE)  // 12500
#define RANGED_SLICES 128            // blocks per range for ranged kernels

__device__ __forceinline__ float4 f4add(float4 a, float4 b) {
    return make_float4(a.x + b.x, a.y + b.y, a.z + b.z, a.w + b.w);
}

// ---------------- CSR build: ranged histogram -> scan -> ranged fill ----------------

__global__ __launch_bounds__(256) void zero_counts(int* counts, int n) {
    int i = blockIdx.x * blockDim.x + threadIdx.x;
    if (i < n) counts[i] = 0;
}

// Each block handles dst-range (blockIdx&7); slices grid-stride the edge list.
// All scattered atomics for a range stay within ~1 XCD's L2 (blockIdx%8 ~ XCD id).
__global__ __launch_bounds__(256) void hist_ranged(const int* __restrict__ dst,
                                                   int* counts, int e) {
    const int range = blockIdx.x & (NRANGE - 1);
    const int slice = blockIdx.x >> 3;
    const int nslices = gridDim.x >> 3;
    const int lo = range * RANGE_SZ, hi = lo + RANGE_SZ;
    const int step = nslices * 256;
    for (int i = slice * 256 + threadIdx.x; i < e; i += step) {
        int d = dst[i];
        if (d >= lo && d < hi) atomicAdd(&counts[d], 1);
    }
}

__global__ __launch_bounds__(256) void counts_to_dinv(const int* __restrict__ counts,
                                                      float* __restrict__ dinv, int n) {
    int i = blockIdx.x * blockDim.x + threadIdx.x;
    if (i < n) dinv[i] = rsqrtf((float)(counts[i] + 1));
}

__global__ __launch_bounds__(SCAN_BLOCK) void block_sums(const int* __restrict__ counts,
                                                         int* __restrict__ bsum, int n) {
    __shared__ int sm[SCAN_BLOCK];
    int i = blockIdx.x * SCAN_BLOCK + threadIdx.x;
    sm[threadIdx.x] = (i < n) ? counts[i] : 0;
    __syncthreads();
    for (int s = SCAN_BLOCK / 2; s > 0; s >>= 1) {
        if (threadIdx.x < s) sm[threadIdx.x] += sm[threadIdx.x + s];
        __syncthreads();
    }
    if (threadIdx.x == 0) bsum[blockIdx.x] = sm[0];
}

// parallel exclusive scan of ~391 block sums (one 512-thread block, Hillis-Steele)
__global__ __launch_bounds__(512) void scan_bsums_par(int* bsum, int nb) {
    __shared__ int sm[512];
    const int t = threadIdx.x;
    int v = (t < nb) ? bsum[t] : 0;
    sm[t] = v;
    __syncthreads();
    for (int off = 1; off < 512; off <<= 1) {
        int u = (t >= off) ? sm[t - off] : 0;
        __syncthreads();
        sm[t] += u;
        __syncthreads();
    }
    if (t < nb) bsum[t] = sm[t] - v;  // exclusive
}

__global__ __launch_bounds__(SCAN_BLOCK) void make_row_ptr(const int* __restrict__ counts,
                                                           const int* __restrict__ bsum,
                                                           int* __restrict__ row_ptr,
                                                           int* __restrict__ cursor, int n, int e) {
    __shared__ int sm[SCAN_BLOCK];
    int i = blockIdx.x * SCAN_BLOCK + threadIdx.x;
    sm[threadIdx.x] = (i < n) ? counts[i] : 0;
    __syncthreads();
    int pre = 0;
    for (int j = 0; j < (int)threadIdx.x; ++j) pre += sm[j];
    if (i < n) {
        int rp = bsum[blockIdx.x] + pre;
        row_ptr[i] = rp;
        cursor[i] = rp;
    }
    if (i == n - 1) row_ptr[n] = e;
}

// ranged fill: same partitioning as hist_ranged; scattered writes stay in-range.
__global__ __launch_bounds__(256) void fill_ranged(const int* __restrict__ src,
                                                   const int* __restrict__ dst,
                                                   int* cursor,
                                                   int* __restrict__ csr_src, int e) {
    const int range = blockIdx.x & (NRANGE - 1);
    const int slice = blockIdx.x >> 3;
    const int nslices = gridDim.x >> 3;
    const int lo = range * RANGE_SZ, hi = lo + RANGE_SZ;
    const int step = nslices * 256;
    for (int i = slice * 256 + threadIdx.x; i < e; i += step) {
        int d = dst[i];
        if (d >= lo && d < hi) {
            int pos = atomicAdd(&cursor[d], 1);
            csr_src[pos] = src[i];
        }
    }
}

// ---------------- register-tiled GEMM: Y = dinv[row] * (X[N,K] @ W[K,COUT]) ----------------

template <int K, int COUT>
__global__ __launch_bounds__(256) void gemm_rt(const float* __restrict__ X,
                                               const float* __restrict__ W,
                                               const float* __restrict__ dinv,
                                               float* __restrict__ Y, int n) {
    constexpr int KC = 64;
    constexpr int S = KC + 4;
    constexpr int NCHUNK = K / KC;
    __shared__ float Xl[64 * S];
    __shared__ float Wl[KC * COUT];

    const int t = threadIdx.x;
    const int row0 = blockIdx.x * 64;
    const int cg = (t & 15) * 4;
    const int rg = (t >> 4) * 4;

    float acc[4][4] = {};

#pragma unroll
    for (int ch = 0; ch < NCHUNK; ++ch) {
        const int k0 = ch * KC;
        for (int i = t; i < 64 * KC / 4; i += 256) {
            int r = i >> 4;
            int k = (i & 15) * 4;
            int grow = row0 + r;
            if (grow >= n) grow = n - 1;
            float4 v = *(const float4*)(X + (size_t)grow * K + k0 + k);
            *(float4*)(Xl + r * S + k) = v;
        }
        for (int i = t; i < KC * COUT / 4; i += 256) {
            float4 v = *(const float4*)(W + (size_t)k0 * COUT + (size_t)i * 4);
            *(float4*)(Wl + i * 4) = v;
        }
        __syncthreads();

        if (cg < COUT) {
#pragma unroll 4
            for (int k = 0; k < KC; ++k) {
                float4 w = *(const float4*)(Wl + k * COUT + cg);
                float x0 = Xl[(rg + 0) * S + k];
                float x1 = Xl[(rg + 1) * S + k];
                float x2 = Xl[(rg + 2) * S + k];
                float x3 = Xl[(rg + 3) * S + k];
                acc[0][0] += x0 * w.x; acc[0][1] += x0 * w.y; acc[0][2] += x0 * w.z; acc[0][3] += x0 * w.w;
                acc[1][0] += x1 * w.x; acc[1][1] += x1 * w.y; acc[1][2] += x1 * w.z; acc[1][3] += x1 * w.w;
                acc[2][0] += x2 * w.x; acc[2][1] += x2 * w.y; acc[2][2] += x2 * w.z; acc[2][3] += x2 * w.w;
                acc[3][0] += x3 * w.x; acc[3][1] += x3 * w.y; acc[3][2] += x3 * w.z; acc[3][3] += x3 * w.w;
            }
        }
        __syncthreads();
    }

    if (cg < COUT) {
#pragma unroll
        for (int r = 0; r < 4; ++r) {
            int row = row0 + rg + r;
            if (row < n) {
                float d = dinv[row];
                float4 o = { d * acc[r][0], d * acc[r][1], d * acc[r][2], d * acc[r][3] };
                *(float4*)(Y + (size_t)row * COUT + cg) = o;
            }
        }
    }
}

// ---------------- vectorized aggregation, COUT=64 ----------------
// One wave per node. Lane-groups of 16: group g reads edge j+g's row as float4
// (64 lanes x 16B = 4 full 256B rows per issue). Unroll 4 -> 16 edges in flight.
// Butterfly shfl_xor(16,32) reduction combines groups at the end.

template <bool RELU>
__global__ __launch_bounds__(256) void aggregate64v(const float* __restrict__ tS,
                                                    const int* __restrict__ row_ptr,
                                                    const int* __restrict__ csr_src,
                                                    const float* __restrict__ dinv,
                                                    const float* __restrict__ bias,
                                                    float* __restrict__ out, int n) {
    const int lane = threadIdx.x & 63;
    const int node = blockIdx.x * 4 + (threadIdx.x >> 6);
    if (node >= n) return;
    const int g = lane >> 4;
    const int c4 = lane & 15;
    const float4* tS4 = (const float4*)tS;

    const int beg = row_ptr[node];
    const int cnt = row_ptr[node + 1] - beg;

    float4 a0 = {0,0,0,0}, a1 = {0,0,0,0}, a2 = {0,0,0,0}, a3 = {0,0,0,0};

    for (int j0 = 0; j0 < cnt; j0 += 64) {
        const int m = min(64, cnt - j0);
        int sj = (lane < m) ? csr_src[beg + j0 + lane] : 0;

        int j = 0;
        for (; j + 16 <= m; j += 16) {
            int e0 = __shfl(sj, j + g);
            int e1 = __shfl(sj, j + 4 + g);
            int e2 = __shfl(sj, j + 8 + g);
            int e3 = __shfl(sj, j + 12 + g);
            float4 v0 = tS4[(size_t)e0 * 16 + c4];
            float4 v1 = tS4[(size_t)e1 * 16 + c4];
            float4 v2 = tS4[(size_t)e2 * 16 + c4];
            float4 v3 = tS4[(size_t)e3 * 16 + c4];
            a0 = f4add(a0, v0); a1 = f4add(a1, v1);
            a2 = f4add(a2, v2); a3 = f4add(a3, v3);
        }
        for (; j + 4 <= m; j += 4) {
            int e0 = __shfl(sj, j + g);
            float4 v0 = tS4[(size_t)e0 * 16 + c4];
            a0 = f4add(a0, v0);
        }
        if (j < m) {  // tail: 1..3 edges, group g active iff j+g < m
            int idx = j + g;
            int e0 = __shfl(sj, idx < m ? idx : m - 1);
            float4 v = tS4[(size_t)e0 * 16 + c4];
            if (idx < m) a0 = f4add(a0, v);
        }
    }

    float4 s = f4add(f4add(a0, a1), f4add(a2, a3));
#pragma unroll
    for (int off = 16; off < 64; off <<= 1) {
        s.x += __shfl_xor(s.x, off);
        s.y += __shfl_xor(s.y, off);
        s.z += __shfl_xor(s.z, off);
        s.w += __shfl_xor(s.w, off);
    }

    if (lane < 16) {
        float4 self = tS4[(size_t)node * 16 + c4];
        float4 b = ((const float4*)bias)[c4];
        float d = dinv[node];
        float4 o;
        o.x = b.x + d * (s.x + self.x);
        o.y = b.y + d * (s.y + self.y);
        o.z = b.z + d * (s.z + self.z);
        o.w = b.w + d * (s.w + self.w);
        if (RELU) {
            o.x = fmaxf(o.x, 0.f); o.y = fmaxf(o.y, 0.f);
            o.z = fmaxf(o.z, 0.f); o.w = fmaxf(o.w, 0.f);
        }
        ((float4*)out)[(size_t)node * 16 + c4] = o;
    }
}

// ---------------- vectorized aggregation, COUT=40 (float2, 20-lane groups x3) ----------------

__global__ __launch_bounds__(256) void aggregate40v(const float* __restrict__ tS,
                                                    const int* __restrict__ row_ptr,
                                                    const int* __restrict__ csr_src,
                                                    const float* __restrict__ dinv,
                                                    const float* __restrict__ bias,
                                                    float* __restrict__ out, int n) {
    const int lane = threadIdx.x & 63;
    const int node = blockIdx.x * 4 + (threadIdx.x >> 6);
    if (node >= n) return;
    const int g = lane / 20;          // 0..2 active, lanes 60-63 -> g=3 idle
    const int c2 = lane - 20 * g;     // 0..19
    const bool act = (g < 3);
    const float2* tS2 = (const float2*)tS;

    const int beg = row_ptr[node];
    const int cnt = row_ptr[node + 1] - beg;

    float2 a0 = {0,0}, a1 = {0,0}, a2 = {0,0}, a3 = {0,0};

    for (int j0 = 0; j0 < cnt; j0 += 64) {
        const int m = min(64, cnt - j0);
        int sj = (lane < m) ? csr_src[beg + j0 + lane] : 0;

        int j = 0;
        for (; j + 12 <= m; j += 12) {
            int i0 = j + g, i1 = j + 3 + g, i2 = j + 6 + g, i3 = j + 9 + g;
            int e0 = __shfl(sj, i0 < m ? i0 : 0);
            int e1 = __shfl(sj, i1 < m ? i1 : 0);
            int e2 = __shfl(sj, i2 < m ? i2 : 0);
            int e3 = __shfl(sj, i3 < m ? i3 : 0);
            float2 v0 = tS2[(size_t)e0 * 20 + c2];
            float2 v1 = tS2[(size_t)e1 * 20 + c2];
            float2 v2 = tS2[(size_t)e2 * 20 + c2];
            float2 v3 = tS2[(size_t)e3 * 20 + c2];
            if (act) {
                a0.x += v0.x; a0.y += v0.y;
                a1.x += v1.x; a1.y += v1.y;
                a2.x += v2.x; a2.y += v2.y;
                a3.x += v3.x; a3.y += v3.y;
            }
        }
        for (; j + 3 <= m; j += 3) {
            int i0 = j + g;
            int e0 = __shfl(sj, i0 < m ? i0 : 0);
            float2 v0 = tS2[(size_t)e0 * 20 + c2];
            if (act) { a0.x += v0.x; a0.y += v0.y; }
        }
        if (j < m) {
            int idx = j + g;
            int e0 = __shfl(sj, idx < m ? idx : m - 1);
            float2 v = tS2[(size_t)e0 * 20 + c2];
            if (act && idx < m) { a0.x += v.x; a0.y += v.y; }
        }
    }

    float2 s;
    s.x = (a0.x + a1.x) + (a2.x + a3.x);
    s.y = (a0.y + a1.y) + (a2.y + a3.y);
    // gather groups 1,2 into group 0 (lanes 0..19)
    float sx1 = __shfl(s.x, lane + 20), sy1 = __shfl(s.y, lane + 20);
    float sx2 = __shfl(s.x, lane + 40), sy2 = __shfl(s.y, lane + 40);
    if (lane < 20) {
        s.x += sx1 + sx2;
        s.y += sy1 + sy2;
        float2 self = tS2[(size_t)node * 20 + c2];
        float2 b = ((const float2*)bias)[c2];
        float d = dinv[node];
        float2 o;
        o.x = b.x + d * (s.x + self.x);
        o.y = b.y + d * (s.y + self.y);
        ((float2*)out)[(size_t)node * 20 + c2] = o;
    }
}

// ---------------- launch ----------------

extern "C" void kernel_launch(void* const* d_in, const int* in_sizes, int n_in,
                              void* d_out, int out_size, void* d_ws, size_t ws_size,
                              hipStream_t stream) {
    const float* x  = (const float*)d_in[0];
    const int*   ei = (const int*)d_in[1];
    const int*   src = ei;
    const int*   dst = ei + N_EDGES;
    const float* W1 = (const float*)d_in[2];
    const float* b1 = (const float*)d_in[3];
    const float* W2 = (const float*)d_in[4];
    const float* b2 = (const float*)d_in[5];
    const float* W3 = (const float*)d_in[6];
    const float* b3 = (const float*)d_in[7];
    float* out = (float*)d_out;

    const int N = N_NODES, E = N_EDGES;

    char* p = (char*)d_ws;
    int*   counts   = (int*)p;              p += (size_t)N * 4;
    float* dinv     = (float*)p;            p += (size_t)N * 4;
    int*   row_ptr  = (int*)p;              p += (size_t)(N + 4) * 4;
    int*   cursor   = (int*)p;              p += (size_t)N * 4;
    int*   bsum     = (int*)p;              p += (size_t)(N_BLOCKS + 1) * 4;
    p = (char*)(((size_t)p + 15) & ~(size_t)15);
    int*   csr_src  = (int*)p;              p += (size_t)E * 4;
    float* bufA     = (float*)p;            p += (size_t)N * 64 * 4;
    float* bufB     = (float*)p;            p += (size_t)N * 64 * 4;

    // ---- CSR build (reused by all 3 layers) ----
    zero_counts<<<(N + 255) / 256, 256, 0, stream>>>(counts, N);
    hist_ranged<<<RANGED_SLICES * NRANGE, 256, 0, stream>>>(dst, counts, E);
    counts_to_dinv<<<(N + 255) / 256, 256, 0, stream>>>(counts, dinv, N);
    block_sums<<<N_BLOCKS, SCAN_BLOCK, 0, stream>>>(counts, bsum, N);
    scan_bsums_par<<<1, 512, 0, stream>>>(bsum, N_BLOCKS);
    make_row_ptr<<<N_BLOCKS, SCAN_BLOCK, 0, stream>>>(counts, bsum, row_ptr, cursor, N, E);
    fill_ranged<<<RANGED_SLICES * NRANGE, 256, 0, stream>>>(src, dst, cursor, csr_src, E);

    const int aggGrid = (N + 3) / 4;
    const int gemmGrid = (N + 63) / 64;

    // layer 1
    gemm_rt<128, 64><<<gemmGrid, 256, 0, stream>>>(x, W1, dinv, bufA, N);
    aggregate64v<true><<<aggGrid, 256, 0, stream>>>(bufA, row_ptr, csr_src, dinv, b1, bufB, N);

    // layer 2
    gemm_rt<64, 64><<<gemmGrid, 256, 0, stream>>>(bufB, W2, dinv, bufA, N);
    aggregate64v<true><<<aggGrid, 256, 0, stream>>>(bufA, row_ptr, csr_src, dinv, b2, bufB, N);

    // layer 3
    gemm_rt<64, 40><<<gemmGrid, 256, 0, stream>>>(bufB, W3, dinv, bufA, N);
    aggregate40v<<<aggGrid, 256, 0, stream>>>(bufA, row_ptr, csr_src, dinv, b3, out, N);
}